// Round 7
// baseline (934.777 us; speedup 1.0000x reference)
//
#include <hip/hip_runtime.h>
#include <hip/hip_bf16.h>

#define CH 64
#define HW 65536
#define NBATCH 16
#define GROUP_ELEMS (8 * HW)
#define GN_EPS 1e-5f

typedef __attribute__((ext_vector_type(8))) short bf16x8;
typedef __attribute__((ext_vector_type(4))) float f32x4;

// ws float-offset layout
#define WS_SUMS   0       // 128*2 floats
#define WS_FRAGS  1024    // 32 frags * 64 lanes * 4 dwords (uint)
#define WS_SCALE  16384   // 16*64 floats
#define WS_SHIFT  17408   // 16*64 floats

static __device__ __forceinline__ unsigned short f2bf(float f) {
    unsigned u = __float_as_uint(f);
    return (unsigned short)((u + 0x7fffu + ((u >> 16) & 1u)) >> 16);  // RNE
}
static __device__ __forceinline__ unsigned short f2bf_hw(float f) {
    return __bfloat16_as_ushort(__float2bfloat16(f));  // RNE, hw cvt(_pk)
}
static __device__ __forceinline__ float bf2f(unsigned h) {
    return __uint_as_float(h << 16);
}
// XOR-swizzle: spread 128B rows across banks (bits 7..9 = pix&7 -> bits 4..6)
#define SWZ(a) ((a) ^ ((((a) >> 7) & 7) << 4))

// ---------------- Kernel A: per-(batch,group) sum / sumsq ----------------
__global__ __launch_bounds__(256, 8) void gn_stats(const float* __restrict__ x,
                                                   float* __restrict__ ws) {
    const int blk = blockIdx.x, grp = blk >> 4, split = blk & 15, tid = threadIdx.x;
    const float4* x4 = (const float4*)x + (size_t)grp * (GROUP_ELEMS / 4)
                                        + (size_t)split * (GROUP_ELEMS / 64);
    float s = 0.f, ss = 0.f;
    #pragma unroll
    for (int i = 0; i < 32; ++i) {
        float4 v = x4[i * 256 + tid];
        s  += v.x + v.y + v.z + v.w;
        ss += v.x * v.x + v.y * v.y + v.z * v.z + v.w * v.w;
    }
    #pragma unroll
    for (int o = 32; o > 0; o >>= 1) {
        s += __shfl_down(s, o, 64);
        ss += __shfl_down(ss, o, 64);
    }
    if ((tid & 63) == 0) {
        atomicAdd(&ws[grp * 2 + 0], s);
        atomicAdd(&ws[grp * 2 + 1], ss);
    }
}

// ---------------- Kernel B: weight-fragment split + GN scale/shift ----------------
__global__ __launch_bounds__(64) void gn_setup(const float* __restrict__ w1,
                                               const float* __restrict__ w2,
                                               const float* __restrict__ gamma,
                                               const float* __restrict__ beta,
                                               float* __restrict__ ws) {
    const int bid = blockIdx.x, l = threadIdx.x;
    if (bid < 16) {
        const int mat = bid >> 3, mt = (bid >> 1) & 3, kt = bid & 1;
        const float* w = mat ? w2 : w1;
        const int row = mt * 16 + (l & 15);
        const float* p = w + row * 64 + kt * 32 + (l >> 4) * 8;
        unsigned hi[4], lo[4];
        #pragma unroll
        for (int j = 0; j < 4; ++j) {
            float v0 = p[2 * j], v1 = p[2 * j + 1];
            unsigned h0 = f2bf(v0), h1 = f2bf(v1);
            unsigned l0 = f2bf(v0 - bf2f(h0)), l1 = f2bf(v1 - bf2f(h1));
            hi[j] = h0 | (h1 << 16);
            lo[j] = l0 | (l1 << 16);
        }
        unsigned* fr = (unsigned*)ws + WS_FRAGS;
        const int fhi = (mat * 2 + 0) * 8 + mt * 2 + kt;
        const int flo = (mat * 2 + 1) * 8 + mt * 2 + kt;
        *(uint4*)(fr + fhi * 256 + l * 4) = make_uint4(hi[0], hi[1], hi[2], hi[3]);
        *(uint4*)(fr + flo * 256 + l * 4) = make_uint4(lo[0], lo[1], lo[2], lo[3]);
    } else {
        const int c = l, g = c >> 3;
        const float ga = gamma[c], be = beta[c], invn = 1.f / (float)GROUP_ELEMS;
        for (int b = 0; b < NBATCH; ++b) {
            float s  = ws[(b * 8 + g) * 2 + 0];
            float ss = ws[(b * 8 + g) * 2 + 1];
            float m  = s * invn;
            float var = ss * invn - m * m;
            float rs = rsqrtf(var + GN_EPS);
            float A = rs * ga;
            ws[WS_SCALE + b * 64 + c] = A;
            ws[WS_SHIFT + b * 64 + c] = be - m * A;
        }
    }
}

// ---------------- Kernel C: fused GN-apply + FFN (MFMA) + residual ----------------
// 2048 blocks x 4 waves. Wave: 8 tiles of 16 pixels. Per tile:
//   load x (16 dword/lane) -> normalize -> split bf16 hi/lo -> X in LDS (swizzled)
//   GEMM1 (A-frags streamed from L2) -> residual read -> relu/split H over X
//   GEMM2 -> +residual store.  Weights NOT register-resident: 3 waves/SIMD.
__global__ __launch_bounds__(256, 3) void fused_gn_ffn(
        const float* __restrict__ x,
        const float* __restrict__ b1g, const float* __restrict__ b2g,
        const float* __restrict__ ws, float* __restrict__ out) {

    __shared__ __align__(16) char lds[16384];
    const int tid = threadIdx.x, wid = tid >> 6, l = tid & 63;
    const int b = blockIdx.x >> 7;
    const int pbase = (blockIdx.x & 127) * 512 + wid * 128;  // wave's 128 pixels

    char* X_hi = lds + wid * 4096;
    char* X_lo = X_hi + 2048;

    const uint4* fr4 = (const uint4*)((const unsigned*)ws + WS_FRAGS) + l;
    // frag f base: fr4 + f*64

    // biases in C/D layout: rows mt*16 + (l>>4)*4 .. +4
    f32x4 b1v[4], b2v[4];
    #pragma unroll
    for (int mt = 0; mt < 4; ++mt) {
        const int r = mt * 16 + (l >> 4) * 4;
        b1v[mt] = *(const f32x4*)(b1g + r);
        b2v[mt] = *(const f32x4*)(b2g + r);
    }

    // per-lane GN scale/shift for its 2 channel-octs (loaded once)
    float sca[16], sha[16];
    const float* scale = ws + WS_SCALE + b * 64;
    const float* shift = ws + WS_SHIFT + b * 64;
    #pragma unroll
    for (int a = 0; a < 2; ++a) {
        const int oct = (l >> 4) + 4 * a;
        *(f32x4*)(sca + a * 8)     = *(const f32x4*)(scale + oct * 8);
        *(f32x4*)(sca + a * 8 + 4) = *(const f32x4*)(scale + oct * 8 + 4);
        *(f32x4*)(sha + a * 8)     = *(const f32x4*)(shift + oct * 8);
        *(f32x4*)(sha + a * 8 + 4) = *(const f32x4*)(shift + oct * 8 + 4);
    }

    #pragma unroll 2
    for (int t = 0; t < 8; ++t) {
        const int pix0 = pbase + t * 16;
        const int p = l & 15;

        // ---- stage: load 16 ch/lane, normalize, split, write X ----
        #pragma unroll
        for (int a = 0; a < 2; ++a) {
            const int oct = (l >> 4) + 4 * a;
            const float* gp = x + ((size_t)(b * 64 + oct * 8)) * HW + pix0 + p;
            float xn[8];
            #pragma unroll
            for (int j = 0; j < 8; ++j)
                xn[j] = fmaf(gp[(size_t)j * HW], sca[a * 8 + j], sha[a * 8 + j]);
            unsigned hiw[4], low[4];
            #pragma unroll
            for (int j = 0; j < 4; ++j) {
                unsigned h0 = f2bf_hw(xn[2 * j]), h1 = f2bf_hw(xn[2 * j + 1]);
                unsigned l0 = f2bf_hw(xn[2 * j] - bf2f(h0));
                unsigned l1 = f2bf_hw(xn[2 * j + 1] - bf2f(h1));
                hiw[j] = h0 | (h1 << 16);
                low[j] = l0 | (l1 << 16);
            }
            const unsigned ad = (unsigned)(p * 128 + oct * 16);
            *(uint4*)(X_hi + SWZ(ad)) = make_uint4(hiw[0], hiw[1], hiw[2], hiw[3]);
            *(uint4*)(X_lo + SWZ(ad)) = make_uint4(low[0], low[1], low[2], low[3]);
        }

        // ---- B-fragments of X (lane: pixel l&15, k-chunk (l>>4)*8) ----
        const unsigned ba = (unsigned)(p * 128 + (l >> 4) * 16);
        bf16x8 xh0 = __builtin_bit_cast(bf16x8, *(const uint4*)(X_hi + SWZ(ba)));
        bf16x8 xh1 = __builtin_bit_cast(bf16x8, *(const uint4*)(X_hi + SWZ(ba + 64)));
        bf16x8 xl0 = __builtin_bit_cast(bf16x8, *(const uint4*)(X_lo + SWZ(ba)));
        bf16x8 xl1 = __builtin_bit_cast(bf16x8, *(const uint4*)(X_lo + SWZ(ba + 64)));

        // ---- GEMM1: A-frags streamed from L2 ----
        f32x4 acc[4];
        #pragma unroll
        for (int mt = 0; mt < 4; ++mt) {
            bf16x8 ah0 = __builtin_bit_cast(bf16x8, fr4[(0 + mt * 2 + 0) * 64]);
            bf16x8 ah1 = __builtin_bit_cast(bf16x8, fr4[(0 + mt * 2 + 1) * 64]);
            bf16x8 al0 = __builtin_bit_cast(bf16x8, fr4[(8 + mt * 2 + 0) * 64]);
            bf16x8 al1 = __builtin_bit_cast(bf16x8, fr4[(8 + mt * 2 + 1) * 64]);
            f32x4 a = b1v[mt];
            a = __builtin_amdgcn_mfma_f32_16x16x32_bf16(ah0, xh0, a, 0, 0, 0);
            a = __builtin_amdgcn_mfma_f32_16x16x32_bf16(ah1, xh1, a, 0, 0, 0);
            a = __builtin_amdgcn_mfma_f32_16x16x32_bf16(ah0, xl0, a, 0, 0, 0);
            a = __builtin_amdgcn_mfma_f32_16x16x32_bf16(ah1, xl1, a, 0, 0, 0);
            a = __builtin_amdgcn_mfma_f32_16x16x32_bf16(al0, xh0, a, 0, 0, 0);
            a = __builtin_amdgcn_mfma_f32_16x16x32_bf16(al1, xh1, a, 0, 0, 0);
            acc[mt] = a;
        }

        // ---- per-mt: residual read (before overwrite), relu+split H over X ----
        f32x4 acc2[4];
        #pragma unroll
        for (int mt = 0; mt < 4; ++mt) {
            const unsigned ra = (unsigned)(p * 128 + mt * 32 + (l >> 4) * 8);
            uint2 rh = *(const uint2*)(X_hi + SWZ(ra));
            uint2 rl = *(const uint2*)(X_lo + SWZ(ra));
            f32x4 res;
            res[0] = bf2f(rh.x & 0xffffu) + bf2f(rl.x & 0xffffu);
            res[1] = bf2f(rh.x >> 16)     + bf2f(rl.x >> 16);
            res[2] = bf2f(rh.y & 0xffffu) + bf2f(rl.y & 0xffffu);
            res[3] = bf2f(rh.y >> 16)     + bf2f(rl.y >> 16);
            acc2[mt] = b2v[mt] + res;

            float h0 = fmaxf(acc[mt][0], 0.f), h1 = fmaxf(acc[mt][1], 0.f);
            float h2 = fmaxf(acc[mt][2], 0.f), h3 = fmaxf(acc[mt][3], 0.f);
            unsigned a0 = f2bf_hw(h0), a1 = f2bf_hw(h1), a2 = f2bf_hw(h2), a3 = f2bf_hw(h3);
            unsigned c0 = f2bf_hw(h0 - bf2f(a0)), c1 = f2bf_hw(h1 - bf2f(a1));
            unsigned c2 = f2bf_hw(h2 - bf2f(a2)), c3 = f2bf_hw(h3 - bf2f(a3));
            *(uint2*)(X_hi + SWZ(ra)) = make_uint2(a0 | (a1 << 16), a2 | (a3 << 16));
            *(uint2*)(X_lo + SWZ(ra)) = make_uint2(c0 | (c1 << 16), c2 | (c3 << 16));
        }

        // ---- H B-fragments + GEMM2 ----
        bf16x8 hh0 = __builtin_bit_cast(bf16x8, *(const uint4*)(X_hi + SWZ(ba)));
        bf16x8 hh1 = __builtin_bit_cast(bf16x8, *(const uint4*)(X_hi + SWZ(ba + 64)));
        bf16x8 hl0 = __builtin_bit_cast(bf16x8, *(const uint4*)(X_lo + SWZ(ba)));
        bf16x8 hl1 = __builtin_bit_cast(bf16x8, *(const uint4*)(X_lo + SWZ(ba + 64)));
        #pragma unroll
        for (int mt = 0; mt < 4; ++mt) {
            bf16x8 ah0 = __builtin_bit_cast(bf16x8, fr4[(16 + mt * 2 + 0) * 64]);
            bf16x8 ah1 = __builtin_bit_cast(bf16x8, fr4[(16 + mt * 2 + 1) * 64]);
            bf16x8 al0 = __builtin_bit_cast(bf16x8, fr4[(24 + mt * 2 + 0) * 64]);
            bf16x8 al1 = __builtin_bit_cast(bf16x8, fr4[(24 + mt * 2 + 1) * 64]);
            f32x4 a = acc2[mt];
            a = __builtin_amdgcn_mfma_f32_16x16x32_bf16(ah0, hh0, a, 0, 0, 0);
            a = __builtin_amdgcn_mfma_f32_16x16x32_bf16(ah1, hh1, a, 0, 0, 0);
            a = __builtin_amdgcn_mfma_f32_16x16x32_bf16(ah0, hl0, a, 0, 0, 0);
            a = __builtin_amdgcn_mfma_f32_16x16x32_bf16(ah1, hl1, a, 0, 0, 0);
            a = __builtin_amdgcn_mfma_f32_16x16x32_bf16(al0, hh0, a, 0, 0, 0);
            a = __builtin_amdgcn_mfma_f32_16x16x32_bf16(al1, hh1, a, 0, 0, 0);

            const int row = mt * 16 + (l >> 4) * 4;
            float* op = out + ((size_t)(b * 64 + row)) * HW + pix0 + p;
            __builtin_nontemporal_store(a[0], op);
            __builtin_nontemporal_store(a[1], op + HW);
            __builtin_nontemporal_store(a[2], op + 2 * HW);
            __builtin_nontemporal_store(a[3], op + 3 * HW);
        }
    }
}

extern "C" void kernel_launch(void* const* d_in, const int* in_sizes, int n_in,
                              void* d_out, int out_size, void* d_ws, size_t ws_size,
                              hipStream_t stream) {
    const float* x     = (const float*)d_in[0];
    const float* gamma = (const float*)d_in[1];
    const float* beta  = (const float*)d_in[2];
    const float* w1    = (const float*)d_in[3];
    const float* b1    = (const float*)d_in[4];
    const float* w2    = (const float*)d_in[5];
    const float* b2    = (const float*)d_in[6];
    float* out = (float*)d_out;
    float* ws  = (float*)d_ws;

    hipMemsetAsync(ws, 0, 256 * sizeof(float), stream);
    gn_stats<<<2048, 256, 0, stream>>>(x, ws);
    gn_setup<<<17, 64, 0, stream>>>(w1, w2, gamma, beta, ws);
    fused_gn_ffn<<<2048, 256, 0, stream>>>(x, b1, b2, ws, out);
}